// Round 12
// baseline (210.753 us; speedup 1.0000x reference)
//
#include <hip/hip_runtime.h>

// WiredRNN one step. Coarse-partition + per-range LDS f32 accumulation.
// Key insight vs rounds 7/9 (which died at 1.5% hit rate): partition FIRST,
// then a per-range block sees 100% relevant records -> no divergence.
// Key insight vs rounds 2-11 (CSR): per-node ordering is never needed --
// LDS accumulators commute. Deletes fine sort, edata, and gather kernel.
//   K0: transpose states->bf16 (N,32)  ||  coarse hist (R ranges of 128)
//   K1: scan R range counts -> bases + cursors
//   K2: partition edges into range-grouped staging (per-block LDS hist,
//       one global atomicAdd per (block,range) reservation)
//   K3: per-range: LDS acc[128][33] += w*state (2 ds_add per record-lane),
//       then tanh/bias/response, x-clamp, write ns (B,N) + y slice.
// inputs: 0:x(B,512) 1:states(B,N) 2:weight(E) 3:bias(N) 4:response(N)
//         5:edge_src(E int32) 6:edge_dst(E int32)
// out: y(B,256) then new_states(B,N), f32, concatenated flat.

#define BATCH 32
#define N_IN 512
#define N_OUT 256
#define RB_LOG 7
#define RB (1 << RB_LOG)   // 128 nodes per range
#define MAXR 512           // max ranges (N <= 65536)

static __device__ __forceinline__ unsigned short f2bf(float f) {
    unsigned u = __float_as_uint(f);
    unsigned r = (u + 0x7fffu + ((u >> 16) & 1u)) >> 16;   // RNE
    return (unsigned short)r;
}

// ---- K0: fused {transpose (B,N)->(N,32) bf16} + {coarse hist} ----
__global__ __launch_bounds__(1024)
void k0_kernel(const float* __restrict__ s, unsigned short* __restrict__ sTb,
               int N, int tgrid,
               const int* __restrict__ edge_dst, int* __restrict__ ccounts,
               int R, int E, int hchunk) {
    __shared__ int shbuf[1056];          // transpose tile (32*33 f32) / hist
    if ((int)blockIdx.x < tgrid) {
        float* tile = (float*)shbuf;
        int tx = threadIdx.x & 31;
        int ty = threadIdx.x >> 5;       // 0..31
        int n0 = blockIdx.x * 32;
        int n = n0 + tx;
        tile[ty * 33 + tx] = (n < N) ? s[(size_t)ty * N + n] : 0.f;  // ty=b
        __syncthreads();
        int nn = n0 + ty;
        if (nn < N) sTb[(size_t)nn * 32 + tx] = f2bf(tile[tx * 33 + ty]);
        return;
    }
    int hb = blockIdx.x - tgrid;
    for (int i = threadIdx.x; i < MAXR; i += 1024) shbuf[i] = 0;
    __syncthreads();
    int e0 = hb * hchunk, e1 = min(e0 + hchunk, E);
    for (int e = e0 + (int)threadIdx.x * 4; e < e1; e += 1024 * 4) {
        if (e + 3 < e1) {
            int4 d4 = *reinterpret_cast<const int4*>(edge_dst + e);
            int dd[4] = {d4.x, d4.y, d4.z, d4.w};
#pragma unroll
            for (int j = 0; j < 4; ++j)
                if (dd[j] >= N_IN) atomicAdd(&shbuf[dd[j] >> RB_LOG], 1);
        } else {
            for (int j = 0; j < 4 && e + j < e1; ++j) {
                int d = edge_dst[e + j];
                if (d >= N_IN) atomicAdd(&shbuf[d >> RB_LOG], 1);
            }
        }
    }
    __syncthreads();
    for (int i = threadIdx.x; i < R; i += 1024)
        if (shbuf[i]) atomicAdd(&ccounts[i], shbuf[i]);
}

// ---- K1: exclusive scan of R<=512 range counts -> bases, cursors ----
__global__ void k1_kernel(const int* __restrict__ ccounts,
                          int* __restrict__ bases, int* __restrict__ cursors,
                          int R) {
    __shared__ int sh[MAXR];
    int tid = threadIdx.x;
    int v = (tid < R) ? ccounts[tid] : 0;
    sh[tid] = v;
    __syncthreads();
    for (int off = 1; off < MAXR; off <<= 1) {
        int t = (tid >= off) ? sh[tid - off] : 0;
        __syncthreads();
        sh[tid] += t;
        __syncthreads();
    }
    int excl = sh[tid] - v;
    if (tid < R) { bases[tid] = excl; cursors[tid] = excl; }
    if (tid == R - 1) bases[R] = sh[tid];
}

// ---- K2: partition edges into range-grouped staging ----
__global__ __launch_bounds__(1024)
void k2_kernel(const int* __restrict__ edge_src,
               const int* __restrict__ edge_dst,
               const float* __restrict__ weight,
               int* __restrict__ cursors,
               int2* __restrict__ staging, int E, int R, int pchunk) {
    __shared__ int h[MAXR];
    __shared__ int lcur[MAXR];
    for (int i = threadIdx.x; i < MAXR; i += 1024) h[i] = 0;
    __syncthreads();
    int e0 = blockIdx.x * pchunk, e1 = min(e0 + pchunk, E);
    // pass A: local counts (dst only; chunk stays L1/L2-hot for pass B)
    for (int e = e0 + (int)threadIdx.x * 4; e < e1; e += 1024 * 4) {
        if (e + 3 < e1) {
            int4 d4 = *reinterpret_cast<const int4*>(edge_dst + e);
            int dd[4] = {d4.x, d4.y, d4.z, d4.w};
#pragma unroll
            for (int j = 0; j < 4; ++j)
                if (dd[j] >= N_IN) atomicAdd(&h[dd[j] >> RB_LOG], 1);
        } else {
            for (int j = 0; j < 4 && e + j < e1; ++j) {
                int d = edge_dst[e + j];
                if (d >= N_IN) atomicAdd(&h[d >> RB_LOG], 1);
            }
        }
    }
    __syncthreads();
    // reserve exact contiguous slices (one global atomic per non-empty range)
    for (int i = threadIdx.x; i < R; i += 1024) {
        int c = h[i];
        lcur[i] = c ? atomicAdd(&cursors[i], c) : 0;
    }
    __syncthreads();
    // pass B: place packed records {(dlow<<16)|src, w}
    for (int e = e0 + (int)threadIdx.x * 4; e < e1; e += 1024 * 4) {
        if (e + 3 < e1) {
            int4 d4 = *reinterpret_cast<const int4*>(edge_dst + e);
            int4 s4 = *reinterpret_cast<const int4*>(edge_src + e);
            float4 w4 = *reinterpret_cast<const float4*>(weight + e);
            int dd[4] = {d4.x, d4.y, d4.z, d4.w};
            int ss[4] = {s4.x, s4.y, s4.z, s4.w};
            float ww[4] = {w4.x, w4.y, w4.z, w4.w};
#pragma unroll
            for (int j = 0; j < 4; ++j) {
                if (dd[j] >= N_IN) {
                    int pos = atomicAdd(&lcur[dd[j] >> RB_LOG], 1);
                    staging[pos] = make_int2(((dd[j] & (RB - 1)) << 16) | ss[j],
                                             __float_as_int(ww[j]));
                }
            }
        } else {
            for (int j = 0; j < 4 && e + j < e1; ++j) {
                int d = edge_dst[e + j];
                if (d >= N_IN) {
                    int pos = atomicAdd(&lcur[d >> RB_LOG], 1);
                    staging[pos] = make_int2(((d & (RB - 1)) << 16) | edge_src[e + j],
                                             __float_as_int(weight[e + j]));
                }
            }
        }
    }
}

// ---- K3: per-range LDS accumulate + activation + output ----
// wave layout: p = lane>>4 (4 records/wave-iter), q = lane&15 (batch pair)
__global__ __launch_bounds__(1024)
void k3_kernel(const unsigned short* __restrict__ sTb,
               const int2* __restrict__ staging,
               const int* __restrict__ bases,
               const float* __restrict__ x,
               const float* __restrict__ bias,
               const float* __restrict__ response,
               float* __restrict__ ns, float* __restrict__ y, int N) {
    __shared__ float acc[RB * 33];
    int r = blockIdx.x;
    int base = r * RB;
    for (int i = threadIdx.x; i < RB * 33; i += 1024) acc[i] = 0.f;
    __syncthreads();

    int b0 = bases[r], b1 = bases[r + 1];
    int wid  = threadIdx.x >> 6;      // 0..15
    int lane = threadIdx.x & 63;
    int q = lane & 15;                // batches 2q, 2q+1
    int p = lane >> 4;                // record slot in wave-iter
    for (int i = b0 + wid * 4 + p; i < b1; i += 16 * 4) {
        int2 rec = staging[i];        // broadcast within 16-lane group
        int src  = rec.x & 0xffff;
        int dlow = ((unsigned)rec.x) >> 16;
        float w  = __int_as_float(rec.y);
        unsigned u = *reinterpret_cast<const unsigned*>(
            sTb + (size_t)src * 32 + 2 * q);
        float* ap = &acc[dlow * 33 + 2 * q];
        atomicAdd(ap,     w * __uint_as_float(u << 16));
        atomicAdd(ap + 1, w * __uint_as_float(u & 0xffff0000u));
    }
    __syncthreads();

    // epilogue: 4096 values; consecutive tid -> consecutive node (coalesced)
    for (int v = threadIdx.x; v < RB * BATCH; v += 1024) {
        int i = v & (RB - 1);
        int b = v >> RB_LOG;
        int node = base + i;
        if (node >= N) continue;
        float val;
        if (node < N_IN)
            val = x[b * N_IN + node];
        else
            val = tanhf(bias[node] + response[node] * acc[i * 33 + b]);
        ns[(size_t)b * N + node] = val;
        int k = node - (N - N_OUT);
        if (k >= 0) y[b * N_OUT + k] = val;
    }
}

// ---- last-resort fallback (round-1) kernels ----
__global__ void edge_kernel_fb(const float* __restrict__ states,
                               const float* __restrict__ weight,
                               const int* __restrict__ edge_src,
                               const int* __restrict__ edge_dst,
                               float* __restrict__ agg, int E, int N) {
    int e = blockIdx.x * blockDim.x + threadIdx.x;
    if (e >= E) return;
    int s = edge_src[e];
    int d = edge_dst[e];
    float w = weight[e];
#pragma unroll
    for (int b = 0; b < BATCH; ++b)
        atomicAdd(agg + (size_t)b * N + d, w * states[(size_t)b * N + s]);
}

__global__ void finish_kernel_fb(const float* __restrict__ x,
                                 const float* __restrict__ agg,
                                 const float* __restrict__ bias,
                                 const float* __restrict__ response,
                                 float* __restrict__ y, float* __restrict__ ns,
                                 int N) {
    int n = blockIdx.x * blockDim.x + threadIdx.x;
    int b = blockIdx.y;
    if (n >= N) return;
    float v;
    if (n < N_IN) v = x[b * N_IN + n];
    else          v = tanhf(bias[n] + response[n] * agg[(size_t)b * N + n]);
    ns[(size_t)b * N + n] = v;
    int n0 = N - N_OUT;
    if (n >= n0) y[b * N_OUT + (n - n0)] = v;
}

extern "C" void kernel_launch(void* const* d_in, const int* in_sizes, int n_in,
                              void* d_out, int out_size, void* d_ws, size_t ws_size,
                              hipStream_t stream) {
    const float* x        = (const float*)d_in[0];
    const float* states   = (const float*)d_in[1];
    const float* weight   = (const float*)d_in[2];
    const float* bias     = (const float*)d_in[3];
    const float* response = (const float*)d_in[4];
    const int*   edge_src = (const int*)d_in[5];
    const int*   edge_dst = (const int*)d_in[6];

    int N = in_sizes[3];          // 50000
    int E = in_sizes[5];          // 800000

    float* y  = (float*)d_out;                   // (B, N_OUT)
    float* ns = (float*)d_out + BATCH * N_OUT;   // (B, N)

    int tgrid = (N + 31) / 32;                   // 1563
    int R = (N + RB - 1) / RB;                   // 391

    const int HB = 64;                           // coarse-hist blocks
    const int PB = 128;                          // partition blocks
    int hchunk = (((E + HB - 1) / HB) + 3) & ~3;
    int pchunk = (((E + PB - 1) / PB) + 3) & ~3;

    size_t staging_bytes = ((size_t)E * 8 + 15) & ~(size_t)15;
    size_t sTb_bytes     = ((size_t)N * 32 * 2 + 15) & ~(size_t)15;
    size_t small_bytes   = (size_t)(MAXR + (MAXR + 1) + MAXR) * 4 + 64;
    size_t needed = staging_bytes + sTb_bytes + small_bytes + 64;

    if (ws_size < needed || R > MAXR || N > 65536) {
        // fallback: atomic-scatter path (needs 6.4 MB)
        float* agg = (float*)d_ws;
        hipMemsetAsync(agg, 0, (size_t)BATCH * N * sizeof(float), stream);
        int egrid = (E + 255) / 256;
        edge_kernel_fb<<<egrid, 256, 0, stream>>>(states, weight, edge_src,
                                                  edge_dst, agg, E, N);
        dim3 fgrid((N + 255) / 256, BATCH);
        finish_kernel_fb<<<fgrid, 256, 0, stream>>>(x, agg, bias, response,
                                                    y, ns, N);
        return;
    }

    char* p = (char*)d_ws;
    int2*           staging = (int2*)p;           p += staging_bytes;
    unsigned short* sTb     = (unsigned short*)p; p += sTb_bytes;
    int*            ccounts = (int*)p;            p += MAXR * 4;
    int*            bases   = (int*)p;            p += (MAXR + 1) * 4;
    int*            cursors = (int*)p;

    hipMemsetAsync(ccounts, 0, MAXR * 4, stream);

    // K0: transpose || coarse hist
    k0_kernel<<<tgrid + HB, 1024, 0, stream>>>(states, sTb, N, tgrid,
                                               edge_dst, ccounts, R, E, hchunk);
    // K1: scan R counts -> bases, cursors
    k1_kernel<<<1, MAXR, 0, stream>>>(ccounts, bases, cursors, R);

    // K2: partition into range-grouped staging
    k2_kernel<<<PB, 1024, 0, stream>>>(edge_src, edge_dst, weight,
                                       cursors, staging, E, R, pchunk);

    // K3: per-range LDS accumulate + tanh + clamp + output
    k3_kernel<<<R, 1024, 0, stream>>>(sTb, staging, bases, x,
                                      bias, response, ns, y, N);
}

// Round 13
// 62.614 us; speedup vs baseline: 3.3659x; 3.3659x over previous
//
#include <hip/hip_runtime.h>

// WiredRNN one step. Exact coarse partition (64-node ranges) + fused
// sort-gather-activate kernel. NO f32 atomics anywhere (measured wall:
// 25.6M LDS f32 atomicAdd = 170-180us, r9/r12). All accumulation in
// registers + owner-wave LDS adds.
//   K0 t_hist : transpose states->bf16 (N,32)  ||  per-range hist (int)
//   K1 scan   : exclusive scan of R range counts -> bases, cursors
//   K2 part   : partition edges into exact per-range staging slices
//               (per-block LDS hist + one global atomicAdd per (block,range))
//   K3 accfin : per range r (64 nodes): round-wise {LDS hist+scan+sort of
//               its records} -> each wave register-accumulates 4 nodes
//               (broadcast LDS reads, 64B sTb gathers, shfl reduce) ->
//               acc LDS (owner-only, no atomics) -> tanh/x-clamp -> ns,y.
// inputs: 0:x(B,512) 1:states(B,N) 2:weight(E) 3:bias(N) 4:response(N)
//         5:edge_src(E int32) 6:edge_dst(E int32)
// out: y(B,256) then new_states(B,N), f32, concatenated flat.

#define BATCH 32
#define N_IN 512
#define N_OUT 256
#define RB_LOG 6
#define RB 64            // nodes per range
#define CAPL 2048        // records sorted per round (16KB LDS)
#define MAXR 1024        // max ranges (scan width)

static __device__ __forceinline__ unsigned short f2bf(float f) {
    unsigned u = __float_as_uint(f);
    unsigned r = (u + 0x7fffu + ((u >> 16) & 1u)) >> 16;   // RNE
    return (unsigned short)r;
}

// ---- K0: fused {transpose (B,N)->(N,32) bf16} + {range hist} ----
__global__ __launch_bounds__(1024)
void t_hist_kernel(const float* __restrict__ s, unsigned short* __restrict__ sTb,
                   int N, int tgrid,
                   const int* __restrict__ edge_dst, int* __restrict__ ccounts,
                   int R, int E, int hchunk) {
    __shared__ int shbuf[1056];          // transpose tile (32*33 f32) / hist
    if ((int)blockIdx.x < tgrid) {
        float* tile = (float*)shbuf;
        int tx = threadIdx.x & 31;
        int ty = threadIdx.x >> 5;       // 0..31
        int n0 = blockIdx.x * 32;
        int n = n0 + tx;
        tile[ty * 33 + tx] = (n < N) ? s[(size_t)ty * N + n] : 0.f;  // ty=b
        __syncthreads();
        int nn = n0 + ty;
        if (nn < N) sTb[(size_t)nn * 32 + tx] = f2bf(tile[tx * 33 + ty]);
        return;
    }
    int hb = blockIdx.x - tgrid;
    for (int i = threadIdx.x; i < 1056; i += 1024) shbuf[i] = 0;
    __syncthreads();
    int e0 = hb * hchunk, e1 = min(e0 + hchunk, E);
    for (int e = e0 + (int)threadIdx.x * 4; e < e1; e += 1024 * 4) {
        if (e + 3 < e1) {
            int4 d4 = *reinterpret_cast<const int4*>(edge_dst + e);
            int dd[4] = {d4.x, d4.y, d4.z, d4.w};
#pragma unroll
            for (int j = 0; j < 4; ++j)
                if (dd[j] >= N_IN) atomicAdd(&shbuf[dd[j] >> RB_LOG], 1);
        } else {
            for (int j = 0; j < 4 && e + j < e1; ++j) {
                int d = edge_dst[e + j];
                if (d >= N_IN) atomicAdd(&shbuf[d >> RB_LOG], 1);
            }
        }
    }
    __syncthreads();
    for (int i = threadIdx.x; i < R; i += 1024)
        if (shbuf[i]) atomicAdd(&ccounts[i], shbuf[i]);
}

// ---- K1: exclusive scan of R<=1024 counts -> bases, cursors ----
__global__ __launch_bounds__(1024)
void scan_kernel(const int* __restrict__ ccounts,
                 int* __restrict__ bases, int* __restrict__ cursors, int R) {
    __shared__ int sh[MAXR];
    int tid = threadIdx.x;
    int v = (tid < R) ? ccounts[tid] : 0;
    sh[tid] = v;
    __syncthreads();
    for (int off = 1; off < MAXR; off <<= 1) {
        int t = (tid >= off) ? sh[tid - off] : 0;
        __syncthreads();
        sh[tid] += t;
        __syncthreads();
    }
    int excl = sh[tid] - v;
    if (tid < R) { bases[tid] = excl; cursors[tid] = excl; }
    if (tid == R - 1) bases[R] = sh[tid];
}

// ---- K2: partition edges into exact range-grouped staging ----
__global__ __launch_bounds__(1024)
void part_kernel(const int* __restrict__ edge_src,
                 const int* __restrict__ edge_dst,
                 const float* __restrict__ weight,
                 int* __restrict__ cursors,
                 int2* __restrict__ staging, int E, int R, int pchunk) {
    __shared__ int h[MAXR];
    __shared__ int lcur[MAXR];
    for (int i = threadIdx.x; i < R; i += 1024) h[i] = 0;
    __syncthreads();
    int e0 = blockIdx.x * pchunk, e1 = min(e0 + pchunk, E);
    // pass A: local counts
    for (int e = e0 + (int)threadIdx.x * 4; e < e1; e += 1024 * 4) {
        if (e + 3 < e1) {
            int4 d4 = *reinterpret_cast<const int4*>(edge_dst + e);
            int dd[4] = {d4.x, d4.y, d4.z, d4.w};
#pragma unroll
            for (int j = 0; j < 4; ++j)
                if (dd[j] >= N_IN) atomicAdd(&h[dd[j] >> RB_LOG], 1);
        } else {
            for (int j = 0; j < 4 && e + j < e1; ++j) {
                int d = edge_dst[e + j];
                if (d >= N_IN) atomicAdd(&h[d >> RB_LOG], 1);
            }
        }
    }
    __syncthreads();
    // reserve contiguous sub-slices (one global atomic per non-empty range)
    for (int i = threadIdx.x; i < R; i += 1024) {
        int c = h[i];
        lcur[i] = c ? atomicAdd(&cursors[i], c) : 0;
    }
    __syncthreads();
    // pass B: place packed records {(dlow<<16)|src, w}
    for (int e = e0 + (int)threadIdx.x * 4; e < e1; e += 1024 * 4) {
        if (e + 3 < e1) {
            int4 d4 = *reinterpret_cast<const int4*>(edge_dst + e);
            int4 s4 = *reinterpret_cast<const int4*>(edge_src + e);
            float4 w4 = *reinterpret_cast<const float4*>(weight + e);
            int dd[4] = {d4.x, d4.y, d4.z, d4.w};
            int ss[4] = {s4.x, s4.y, s4.z, s4.w};
            float ww[4] = {w4.x, w4.y, w4.z, w4.w};
#pragma unroll
            for (int j = 0; j < 4; ++j) {
                if (dd[j] >= N_IN) {
                    int pos = atomicAdd(&lcur[dd[j] >> RB_LOG], 1);
                    staging[pos] = make_int2(((dd[j] & (RB - 1)) << 16) | ss[j],
                                             __float_as_int(ww[j]));
                }
            }
        } else {
            for (int j = 0; j < 4 && e + j < e1; ++j) {
                int d = edge_dst[e + j];
                if (d >= N_IN) {
                    int pos = atomicAdd(&lcur[d >> RB_LOG], 1);
                    staging[pos] = make_int2(((d & (RB - 1)) << 16) | edge_src[e + j],
                                             __float_as_int(weight[e + j]));
                }
            }
        }
    }
}

// ---- K3: per-range sort (LDS) + register gather + activation + output ----
__global__ __launch_bounds__(1024)
void accfin_kernel(const unsigned short* __restrict__ sTb,
                   const int2* __restrict__ staging,
                   const int* __restrict__ bases,
                   const float* __restrict__ x,
                   const float* __restrict__ bias,
                   const float* __restrict__ response,
                   float* __restrict__ ns, float* __restrict__ y, int N) {
    __shared__ float acc[RB * 33];       // 8.4 KB, owner-wave writes only
    __shared__ int2  sorted[CAPL];       // 16 KB
    __shared__ int   hstart[RB];
    __shared__ int   hcur[RB];
    int tid = threadIdx.x;
    int r = blockIdx.x;
    int base = r * RB;
    for (int i = tid; i < RB * 33; i += 1024) acc[i] = 0.f;

    int b0 = bases[r], b1 = bases[r + 1];
    int q = tid & 15;                    // batch pair 2q, 2q+1
    int p = (tid >> 4) & 3;              // record slot
    int wid = tid >> 6;                  // wave -> nodes [wid*4, wid*4+4)

    for (int t = b0; t < b1; t += CAPL) {
        int m = min(CAPL, b1 - t);
        if (tid < RB) hstart[tid] = 0;
        __syncthreads();
        for (int i = tid; i < m; i += 1024)
            atomicAdd(&hstart[((unsigned)staging[t + i].x) >> 16], 1);
        __syncthreads();
        int v0 = (tid < RB) ? hstart[tid] : 0;
        for (int off = 1; off < RB; off <<= 1) {
            int tv = (tid < RB && tid >= off) ? hstart[tid - off] : 0;
            __syncthreads();
            if (tid < RB) hstart[tid] += tv;
            __syncthreads();
        }
        if (tid < RB) {
            int ex = hstart[tid] - v0;
            hstart[tid] = ex;
            hcur[tid] = ex;
        }
        __syncthreads();
        for (int i = tid; i < m; i += 1024) {
            int2 rc = staging[t + i];
            int pos = atomicAdd(&hcur[((unsigned)rc.x) >> 16], 1);
            sorted[pos] = rc;
        }
        __syncthreads();
        // gather: wave owns 4 nodes; register accumulate; add to acc (no atomics)
#pragma unroll
        for (int k = 0; k < 4; ++k) {
            int nl = wid * 4 + k;
            int beg = hstart[nl], end = hcur[nl];
            float a0 = 0.f, a1 = 0.f;
            for (int e = beg + p; e < end; e += 4) {
                int2 rc = sorted[e];                       // broadcast read
                float w = __int_as_float(rc.y);
                unsigned u = *reinterpret_cast<const unsigned*>(
                    sTb + (size_t)(rc.x & 0xffff) * 32 + 2 * q);
                a0 += w * __uint_as_float(u << 16);
                a1 += w * __uint_as_float(u & 0xffff0000u);
            }
            a0 += __shfl_xor(a0, 16, 64);
            a0 += __shfl_xor(a0, 32, 64);
            a1 += __shfl_xor(a1, 16, 64);
            a1 += __shfl_xor(a1, 32, 64);
            if ((tid & 63) < 16) {                          // p == 0 lanes
                acc[nl * 33 + 2 * q]     += a0;
                acc[nl * 33 + 2 * q + 1] += a1;
            }
        }
        __syncthreads();
    }

    // epilogue: tanh / x-clamp, coalesced ns + y writes
    for (int v = tid; v < RB * BATCH; v += 1024) {
        int nl = v & (RB - 1);
        int b  = v >> RB_LOG;
        int node = base + nl;
        if (node >= N) continue;
        float val;
        if (node < N_IN)
            val = x[b * N_IN + node];
        else
            val = tanhf(bias[node] + response[node] * acc[nl * 33 + b]);
        ns[(size_t)b * N + node] = val;
        int k = node - (N - N_OUT);
        if (k >= 0) y[b * N_OUT + k] = val;
    }
}

// ---- last-resort fallback (round-1) kernels ----
__global__ void edge_kernel_fb(const float* __restrict__ states,
                               const float* __restrict__ weight,
                               const int* __restrict__ edge_src,
                               const int* __restrict__ edge_dst,
                               float* __restrict__ agg, int E, int N) {
    int e = blockIdx.x * blockDim.x + threadIdx.x;
    if (e >= E) return;
    int s = edge_src[e];
    int d = edge_dst[e];
    float w = weight[e];
#pragma unroll
    for (int b = 0; b < BATCH; ++b)
        atomicAdd(agg + (size_t)b * N + d, w * states[(size_t)b * N + s]);
}

__global__ void finish_kernel_fb(const float* __restrict__ x,
                                 const float* __restrict__ agg,
                                 const float* __restrict__ bias,
                                 const float* __restrict__ response,
                                 float* __restrict__ y, float* __restrict__ ns,
                                 int N) {
    int n = blockIdx.x * blockDim.x + threadIdx.x;
    int b = blockIdx.y;
    if (n >= N) return;
    float v;
    if (n < N_IN) v = x[b * N_IN + n];
    else          v = tanhf(bias[n] + response[n] * agg[(size_t)b * N + n]);
    ns[(size_t)b * N + n] = v;
    int n0 = N - N_OUT;
    if (n >= n0) y[b * N_OUT + (n - n0)] = v;
}

extern "C" void kernel_launch(void* const* d_in, const int* in_sizes, int n_in,
                              void* d_out, int out_size, void* d_ws, size_t ws_size,
                              hipStream_t stream) {
    const float* x        = (const float*)d_in[0];
    const float* states   = (const float*)d_in[1];
    const float* weight   = (const float*)d_in[2];
    const float* bias     = (const float*)d_in[3];
    const float* response = (const float*)d_in[4];
    const int*   edge_src = (const int*)d_in[5];
    const int*   edge_dst = (const int*)d_in[6];

    int N = in_sizes[3];          // 50000
    int E = in_sizes[5];          // 800000

    float* y  = (float*)d_out;                   // (B, N_OUT)
    float* ns = (float*)d_out + BATCH * N_OUT;   // (B, N)

    int tgrid = (N + 31) / 32;                   // 1563
    int R = (N + RB - 1) / RB;                   // 782

    const int HB = 64;                           // hist blocks
    const int PB = 128;                          // partition blocks
    int hchunk = (((E + HB - 1) / HB) + 3) & ~3;
    int pchunk = (((E + PB - 1) / PB) + 3) & ~3;

    size_t staging_bytes = ((size_t)E * 8 + 15) & ~(size_t)15;
    size_t sTb_bytes     = ((size_t)N * 32 * 2 + 15) & ~(size_t)15;
    size_t small_bytes   = (size_t)(MAXR + (MAXR + 1) + MAXR) * 4 + 64;
    size_t needed = staging_bytes + sTb_bytes + small_bytes + 64;

    if (ws_size < needed || R > MAXR || N > 65536) {
        // fallback: atomic-scatter path (needs 6.4 MB)
        float* agg = (float*)d_ws;
        hipMemsetAsync(agg, 0, (size_t)BATCH * N * sizeof(float), stream);
        int egrid = (E + 255) / 256;
        edge_kernel_fb<<<egrid, 256, 0, stream>>>(states, weight, edge_src,
                                                  edge_dst, agg, E, N);
        dim3 fgrid((N + 255) / 256, BATCH);
        finish_kernel_fb<<<fgrid, 256, 0, stream>>>(x, agg, bias, response,
                                                    y, ns, N);
        return;
    }

    char* p = (char*)d_ws;
    int2*           staging = (int2*)p;           p += staging_bytes;
    unsigned short* sTb     = (unsigned short*)p; p += sTb_bytes;
    int*            ccounts = (int*)p;            p += MAXR * 4;
    int*            bases   = (int*)p;            p += (MAXR + 1) * 4;
    int*            cursors = (int*)p;

    hipMemsetAsync(ccounts, 0, (size_t)R * 4, stream);

    // K0: transpose || range hist
    t_hist_kernel<<<tgrid + HB, 1024, 0, stream>>>(states, sTb, N, tgrid,
                                                   edge_dst, ccounts, R, E,
                                                   hchunk);
    // K1: scan -> bases, cursors
    scan_kernel<<<1, MAXR, 0, stream>>>(ccounts, bases, cursors, R);

    // K2: exact partition into per-range staging
    part_kernel<<<PB, 1024, 0, stream>>>(edge_src, edge_dst, weight,
                                         cursors, staging, E, R, pchunk);

    // K3: fused sort + register gather + tanh + output
    accfin_kernel<<<R, 1024, 0, stream>>>(sTb, staging, bases, x,
                                          bias, response, ns, y, N);
}

// Round 14
// 49.134 us; speedup vs baseline: 4.2893x; 1.2743x over previous
//
#include <hip/hip_runtime.h>

// WiredRNN one step. Slab partition (no hist, no scan) + fused
// sort-gather-activate. NO f32 atomics (measured wall: 25.6M LDS f32
// atomicAdd = 170-180us, r9/r12). 3 dispatches total:
//   memset(cursors, R*4)
//   K0 fpart : blocks [0,PB): load 8 edges/thread into REGISTERS, LDS hist
//              by 64-node range, reserve slab slices via one global
//              atomicAdd per (block,range), place records {(dlow<<16)|src,w}
//              into staging[r*CAP + pos]. blocks [PB,..): transpose
//              states (B,N) -> sTb (N,32) bf16.
//   K1 accfin: per range r: LDS hist+scan+sort of its records -> each wave
//              register-accumulates 4 nodes (broadcast LDS reads, 64B sTb
//              line gathers, shfl reduce) -> owner-only LDS acc ->
//              tanh/bias/response, x-clamp -> ns (B,N) + y slice.
// inputs: 0:x(B,512) 1:states(B,N) 2:weight(E) 3:bias(N) 4:response(N)
//         5:edge_src(E int32) 6:edge_dst(E int32)
// out: y(B,256) then new_states(B,N), f32, concatenated flat.

#define BATCH 32
#define N_IN 512
#define N_OUT 256
#define RB_LOG 6
#define RB 64            // nodes per range
#define CAPL 2048        // records sorted per accfin round (16KB LDS)
#define MAXR 2048        // max ranges for part LDS arrays
#define PCH 8192         // edges per partition block (8/thread)

static __device__ __forceinline__ unsigned short f2bf(float f) {
    unsigned u = __float_as_uint(f);
    unsigned r = (u + 0x7fffu + ((u >> 16) & 1u)) >> 16;   // RNE
    return (unsigned short)r;
}

// ---- K0: fused {slab partition} + {transpose (B,N)->(N,32) bf16} ----
__global__ __launch_bounds__(1024)
void fpart_kernel(const float* __restrict__ s, unsigned short* __restrict__ sTb,
                  int N, int PB,
                  const int* __restrict__ edge_src,
                  const int* __restrict__ edge_dst,
                  const float* __restrict__ weight,
                  int* __restrict__ cursors,
                  int2* __restrict__ staging,
                  int E, int R, int CAP) {
    __shared__ int shbuf[MAXR * 2];      // part: h + lcur; transpose: tile
    int tid = threadIdx.x;
    if ((int)blockIdx.x >= PB) {
        // ---------------- transpose ----------------
        float* tile = (float*)shbuf;     // 32*33 f32 = 4.2 KB
        int tx = tid & 31;
        int ty = tid >> 5;               // 0..31
        int n0 = ((int)blockIdx.x - PB) * 32;
        int n = n0 + tx;
        tile[ty * 33 + tx] = (n < N) ? s[(size_t)ty * N + n] : 0.f;  // ty=b
        __syncthreads();
        int nn = n0 + ty;
        if (nn < N) sTb[(size_t)nn * 32 + tx] = f2bf(tile[tx * 33 + ty]);
        return;
    }
    // ---------------- partition ----------------
    int* h    = shbuf;
    int* lcur = shbuf + MAXR;
    for (int i = tid; i < R; i += 1024) h[i] = 0;
    __syncthreads();
    int e0 = blockIdx.x * PCH;
    int e1 = min(e0 + PCH, E);
    int dd[8], ss[8]; float ww[8];
#pragma unroll
    for (int it = 0; it < 2; ++it) {
        int e = e0 + it * 4096 + tid * 4;
#pragma unroll
        for (int j = 0; j < 4; ++j) dd[it * 4 + j] = -1;
        if (e + 4 <= e1) {
            int4 d4 = *reinterpret_cast<const int4*>(edge_dst + e);
            int4 s4 = *reinterpret_cast<const int4*>(edge_src + e);
            float4 w4 = *reinterpret_cast<const float4*>(weight + e);
            dd[it*4+0]=d4.x; dd[it*4+1]=d4.y; dd[it*4+2]=d4.z; dd[it*4+3]=d4.w;
            ss[it*4+0]=s4.x; ss[it*4+1]=s4.y; ss[it*4+2]=s4.z; ss[it*4+3]=s4.w;
            ww[it*4+0]=w4.x; ww[it*4+1]=w4.y; ww[it*4+2]=w4.z; ww[it*4+3]=w4.w;
        } else {
#pragma unroll
            for (int j = 0; j < 4; ++j) {
                if (e + j < e1) {
                    dd[it*4+j] = edge_dst[e + j];
                    ss[it*4+j] = edge_src[e + j];
                    ww[it*4+j] = weight[e + j];
                }
            }
        }
#pragma unroll
        for (int j = 0; j < 4; ++j) {
            int idx = it * 4 + j;
            if (dd[idx] >= N_IN) atomicAdd(&h[dd[idx] >> RB_LOG], 1);
        }
    }
    __syncthreads();
    // reserve slab slices: one global atomic per non-empty (block, range)
    for (int i = tid; i < R; i += 1024) {
        int c = h[i];
        lcur[i] = c ? (i * CAP + atomicAdd(&cursors[i], c)) : 0;
    }
    __syncthreads();
    // place records from registers
#pragma unroll
    for (int idx = 0; idx < 8; ++idx) {
        if (dd[idx] >= N_IN) {
            int rng = dd[idx] >> RB_LOG;
            int pos = atomicAdd(&lcur[rng], 1);
            if (pos < (rng + 1) * CAP)   // overflow clamp (never at 4x mean)
                staging[pos] = make_int2(((dd[idx] & (RB - 1)) << 16) | ss[idx],
                                         __float_as_int(ww[idx]));
        }
    }
}

// ---- K1: per-range sort (LDS) + register gather + activation + output ----
__global__ __launch_bounds__(1024)
void accfin_kernel(const unsigned short* __restrict__ sTb,
                   const int2* __restrict__ staging,
                   const int* __restrict__ cursors,
                   const float* __restrict__ x,
                   const float* __restrict__ bias,
                   const float* __restrict__ response,
                   float* __restrict__ ns, float* __restrict__ y,
                   int N, int CAP) {
    __shared__ float acc[RB * 33];       // 8.4 KB, owner-wave writes only
    __shared__ int2  sorted[CAPL];       // 16 KB
    __shared__ int   hstart[RB];
    __shared__ int   hcur[RB];
    int tid = threadIdx.x;
    int r = blockIdx.x;
    int base = r * RB;
    for (int i = tid; i < RB * 33; i += 1024) acc[i] = 0.f;

    int b0 = r * CAP;
    int b1 = b0 + min(cursors[r], CAP);
    int q = tid & 15;                    // batch pair 2q, 2q+1
    int p = (tid >> 4) & 3;              // record slot
    int wid = tid >> 6;                  // wave -> nodes [wid*4, wid*4+4)

    for (int t = b0; t < b1; t += CAPL) {
        int m = min(CAPL, b1 - t);
        if (tid < RB) hstart[tid] = 0;
        __syncthreads();
        for (int i = tid; i < m; i += 1024)
            atomicAdd(&hstart[((unsigned)staging[t + i].x) >> 16], 1);
        __syncthreads();
        int v0 = (tid < RB) ? hstart[tid] : 0;
        for (int off = 1; off < RB; off <<= 1) {
            int tv = (tid < RB && tid >= off) ? hstart[tid - off] : 0;
            __syncthreads();
            if (tid < RB) hstart[tid] += tv;
            __syncthreads();
        }
        if (tid < RB) {
            int ex = hstart[tid] - v0;
            hstart[tid] = ex;
            hcur[tid] = ex;
        }
        __syncthreads();
        for (int i = tid; i < m; i += 1024) {
            int2 rc = staging[t + i];
            int pos = atomicAdd(&hcur[((unsigned)rc.x) >> 16], 1);
            sorted[pos] = rc;
        }
        __syncthreads();
        // gather: wave owns 4 nodes; register accumulate; owner-only acc adds
#pragma unroll
        for (int k = 0; k < 4; ++k) {
            int nl = wid * 4 + k;
            int beg = hstart[nl], end = hcur[nl];
            float a0 = 0.f, a1 = 0.f;
            for (int e = beg + p; e < end; e += 4) {
                int2 rc = sorted[e];                       // broadcast read
                float w = __int_as_float(rc.y);
                unsigned u = *reinterpret_cast<const unsigned*>(
                    sTb + (size_t)(rc.x & 0xffff) * 32 + 2 * q);
                a0 += w * __uint_as_float(u << 16);
                a1 += w * __uint_as_float(u & 0xffff0000u);
            }
            a0 += __shfl_xor(a0, 16, 64);
            a0 += __shfl_xor(a0, 32, 64);
            a1 += __shfl_xor(a1, 16, 64);
            a1 += __shfl_xor(a1, 32, 64);
            if ((tid & 63) < 16) {                          // p == 0 lanes
                acc[nl * 33 + 2 * q]     += a0;
                acc[nl * 33 + 2 * q + 1] += a1;
            }
        }
        __syncthreads();
    }

    // epilogue: tanh / x-clamp, coalesced ns + y writes
    for (int v = tid; v < RB * BATCH; v += 1024) {
        int nl = v & (RB - 1);
        int b  = v >> RB_LOG;
        int node = base + nl;
        if (node >= N) continue;
        float val;
        if (node < N_IN)
            val = x[b * N_IN + node];
        else
            val = tanhf(bias[node] + response[node] * acc[nl * 33 + b]);
        ns[(size_t)b * N + node] = val;
        int k = node - (N - N_OUT);
        if (k >= 0) y[b * N_OUT + k] = val;
    }
}

// ---- last-resort fallback (round-1) kernels ----
__global__ void edge_kernel_fb(const float* __restrict__ states,
                               const float* __restrict__ weight,
                               const int* __restrict__ edge_src,
                               const int* __restrict__ edge_dst,
                               float* __restrict__ agg, int E, int N) {
    int e = blockIdx.x * blockDim.x + threadIdx.x;
    if (e >= E) return;
    int s = edge_src[e];
    int d = edge_dst[e];
    float w = weight[e];
#pragma unroll
    for (int b = 0; b < BATCH; ++b)
        atomicAdd(agg + (size_t)b * N + d, w * states[(size_t)b * N + s]);
}

__global__ void finish_kernel_fb(const float* __restrict__ x,
                                 const float* __restrict__ agg,
                                 const float* __restrict__ bias,
                                 const float* __restrict__ response,
                                 float* __restrict__ y, float* __restrict__ ns,
                                 int N) {
    int n = blockIdx.x * blockDim.x + threadIdx.x;
    int b = blockIdx.y;
    if (n >= N) return;
    float v;
    if (n < N_IN) v = x[b * N_IN + n];
    else          v = tanhf(bias[n] + response[n] * agg[(size_t)b * N + n]);
    ns[(size_t)b * N + n] = v;
    int n0 = N - N_OUT;
    if (n >= n0) y[b * N_OUT + (n - n0)] = v;
}

extern "C" void kernel_launch(void* const* d_in, const int* in_sizes, int n_in,
                              void* d_out, int out_size, void* d_ws, size_t ws_size,
                              hipStream_t stream) {
    const float* x        = (const float*)d_in[0];
    const float* states   = (const float*)d_in[1];
    const float* weight   = (const float*)d_in[2];
    const float* bias     = (const float*)d_in[3];
    const float* response = (const float*)d_in[4];
    const int*   edge_src = (const int*)d_in[5];
    const int*   edge_dst = (const int*)d_in[6];

    int N = in_sizes[3];          // 50000
    int E = in_sizes[5];          // 800000

    float* y  = (float*)d_out;                   // (B, N_OUT)
    float* ns = (float*)d_out + BATCH * N_OUT;   // (B, N)

    int tgrid = (N + 31) / 32;                   // 1563
    int R  = (N + RB - 1) / RB;                  // 782
    int PB = (E + PCH - 1) / PCH;                // 98

    // slab capacity: 4x mean load, rounded up to CAPL multiple
    int mean = (E + R - 1) / R;                  // ~1023
    int CAP  = ((4 * mean + CAPL - 1) / CAPL) * CAPL;   // 4096

    size_t staging_bytes = ((size_t)R * CAP * 8 + 15) & ~(size_t)15;  // ~25.6MB
    size_t sTb_bytes     = ((size_t)N * 32 * 2 + 15) & ~(size_t)15;
    size_t cur_bytes     = ((size_t)R * 4 + 15) & ~(size_t)15;
    size_t needed = staging_bytes + sTb_bytes + cur_bytes + 64;

    if (ws_size < needed || R > MAXR || N > 65536) {
        // fallback: atomic-scatter path (needs 6.4 MB)
        float* agg = (float*)d_ws;
        hipMemsetAsync(agg, 0, (size_t)BATCH * N * sizeof(float), stream);
        int egrid = (E + 255) / 256;
        edge_kernel_fb<<<egrid, 256, 0, stream>>>(states, weight, edge_src,
                                                  edge_dst, agg, E, N);
        dim3 fgrid((N + 255) / 256, BATCH);
        finish_kernel_fb<<<fgrid, 256, 0, stream>>>(x, agg, bias, response,
                                                    y, ns, N);
        return;
    }

    char* p = (char*)d_ws;
    int2*           staging = (int2*)p;           p += staging_bytes;
    unsigned short* sTb     = (unsigned short*)p; p += sTb_bytes;
    int*            cursors = (int*)p;

    hipMemsetAsync(cursors, 0, (size_t)R * 4, stream);

    // K0: slab partition (blocks [0,PB)) || transpose (blocks [PB, PB+tgrid))
    fpart_kernel<<<PB + tgrid, 1024, 0, stream>>>(
        states, sTb, N, PB, edge_src, edge_dst, weight,
        cursors, staging, E, R, CAP);

    // K1: fused sort + register gather + tanh + output
    accfin_kernel<<<R, 1024, 0, stream>>>(sTb, staging, cursors, x,
                                          bias, response, ns, y, N, CAP);
}

// Round 15
// 46.475 us; speedup vs baseline: 4.5348x; 1.0572x over previous
//
#include <hip/hip_runtime.h>

// WiredRNN one step. Slab partition (no hist, no scan) + fused
// sort-gather-activate. NO f32 atomics (measured wall: 25.6M LDS f32
// atomicAdd = 170-180us, r9/r12). 3 dispatches total:
//   memset(cursors, R*4)
//   K0 fpart : blocks [0,PB): load 8 edges/thread into REGISTERS, LDS hist
//              by 64-node range, reserve slab slices via one global
//              atomicAdd per (block,range), place records {(dlow<<16)|src,w}.
//              blocks [PB,..): transpose states (B,N) -> sTb (N,32) bf16.
//   K1 accfin: 512 thr/block (4 blocks/CU -> all 782 blocks co-resident,
//              no tail round). Per range: LDS hist + WAVE-0 SHUFFLE SCAN
//              (no block barriers) + LDS sort -> each wave register-
//              accumulates 8 nodes (broadcast LDS reads, 64B sTb line
//              gathers, shfl reduce) -> owner-only LDS acc ->
//              tanh/bias/response, x-clamp -> ns (B,N) + y slice.
// inputs: 0:x(B,512) 1:states(B,N) 2:weight(E) 3:bias(N) 4:response(N)
//         5:edge_src(E int32) 6:edge_dst(E int32)
// out: y(B,256) then new_states(B,N), f32, concatenated flat.

#define BATCH 32
#define N_IN 512
#define N_OUT 256
#define RB_LOG 6
#define RB 64            // nodes per range
#define CAPL 2048        // records sorted per accfin round (16KB LDS)
#define MAXR 2048        // max ranges for part LDS arrays
#define PCH 8192         // edges per partition block (8/thread)

static __device__ __forceinline__ unsigned short f2bf(float f) {
    unsigned u = __float_as_uint(f);
    unsigned r = (u + 0x7fffu + ((u >> 16) & 1u)) >> 16;   // RNE
    return (unsigned short)r;
}

// ---- K0: fused {slab partition} + {transpose (B,N)->(N,32) bf16} ----
__global__ __launch_bounds__(1024)
void fpart_kernel(const float* __restrict__ s, unsigned short* __restrict__ sTb,
                  int N, int PB,
                  const int* __restrict__ edge_src,
                  const int* __restrict__ edge_dst,
                  const float* __restrict__ weight,
                  int* __restrict__ cursors,
                  int2* __restrict__ staging,
                  int E, int R, int CAP) {
    __shared__ int shbuf[MAXR * 2];      // part: h + lcur; transpose: tile
    int tid = threadIdx.x;
    if ((int)blockIdx.x >= PB) {
        // ---------------- transpose ----------------
        float* tile = (float*)shbuf;     // 32*33 f32 = 4.2 KB
        int tx = tid & 31;
        int ty = tid >> 5;               // 0..31
        int n0 = ((int)blockIdx.x - PB) * 32;
        int n = n0 + tx;
        tile[ty * 33 + tx] = (n < N) ? s[(size_t)ty * N + n] : 0.f;  // ty=b
        __syncthreads();
        int nn = n0 + ty;
        if (nn < N) sTb[(size_t)nn * 32 + tx] = f2bf(tile[tx * 33 + ty]);
        return;
    }
    // ---------------- partition ----------------
    int* h    = shbuf;
    int* lcur = shbuf + MAXR;
    for (int i = tid; i < R; i += 1024) h[i] = 0;
    __syncthreads();
    int e0 = blockIdx.x * PCH;
    int e1 = min(e0 + PCH, E);
    int dd[8], ss[8]; float ww[8];
#pragma unroll
    for (int it = 0; it < 2; ++it) {
        int e = e0 + it * 4096 + tid * 4;
#pragma unroll
        for (int j = 0; j < 4; ++j) dd[it * 4 + j] = -1;
        if (e + 4 <= e1) {
            int4 d4 = *reinterpret_cast<const int4*>(edge_dst + e);
            int4 s4 = *reinterpret_cast<const int4*>(edge_src + e);
            float4 w4 = *reinterpret_cast<const float4*>(weight + e);
            dd[it*4+0]=d4.x; dd[it*4+1]=d4.y; dd[it*4+2]=d4.z; dd[it*4+3]=d4.w;
            ss[it*4+0]=s4.x; ss[it*4+1]=s4.y; ss[it*4+2]=s4.z; ss[it*4+3]=s4.w;
            ww[it*4+0]=w4.x; ww[it*4+1]=w4.y; ww[it*4+2]=w4.z; ww[it*4+3]=w4.w;
        } else {
#pragma unroll
            for (int j = 0; j < 4; ++j) {
                if (e + j < e1) {
                    dd[it*4+j] = edge_dst[e + j];
                    ss[it*4+j] = edge_src[e + j];
                    ww[it*4+j] = weight[e + j];
                }
            }
        }
#pragma unroll
        for (int j = 0; j < 4; ++j) {
            int idx = it * 4 + j;
            if (dd[idx] >= N_IN) atomicAdd(&h[dd[idx] >> RB_LOG], 1);
        }
    }
    __syncthreads();
    // reserve slab slices: one global atomic per non-empty (block, range)
    for (int i = tid; i < R; i += 1024) {
        int c = h[i];
        lcur[i] = c ? (i * CAP + atomicAdd(&cursors[i], c)) : 0;
    }
    __syncthreads();
    // place records from registers
#pragma unroll
    for (int idx = 0; idx < 8; ++idx) {
        if (dd[idx] >= N_IN) {
            int rng = dd[idx] >> RB_LOG;
            int pos = atomicAdd(&lcur[rng], 1);
            if (pos < (rng + 1) * CAP)   // overflow clamp (never at 4x mean)
                staging[pos] = make_int2(((dd[idx] & (RB - 1)) << 16) | ss[idx],
                                         __float_as_int(ww[idx]));
        }
    }
}

// ---- K1: per-range sort (LDS) + register gather + activation + output ----
// 512 threads: 8 waves x 8 nodes each; wave-0 shuffle scan (no barriers).
__global__ __launch_bounds__(512)
void accfin_kernel(const unsigned short* __restrict__ sTb,
                   const int2* __restrict__ staging,
                   const int* __restrict__ cursors,
                   const float* __restrict__ x,
                   const float* __restrict__ bias,
                   const float* __restrict__ response,
                   float* __restrict__ ns, float* __restrict__ y,
                   int N, int CAP) {
    __shared__ float acc[RB * 33];       // 8.4 KB, owner-wave writes only
    __shared__ int2  sorted[CAPL];       // 16 KB
    __shared__ int   hstart[RB];
    __shared__ int   hcur[RB];
    int tid = threadIdx.x;
    int r = blockIdx.x;
    int base = r * RB;
    for (int i = tid; i < RB * 33; i += 512) acc[i] = 0.f;

    int b0 = r * CAP;
    int b1 = b0 + min(cursors[r], CAP);
    int q = tid & 15;                    // batch pair 2q, 2q+1
    int p = (tid >> 4) & 3;              // record slot
    int wid = tid >> 6;                  // wave -> nodes [wid*8, wid*8+8)
    int lane = tid & 63;

    for (int t = b0; t < b1; t += CAPL) {
        int m = min(CAPL, b1 - t);
        if (tid < RB) hstart[tid] = 0;
        __syncthreads();
        for (int i = tid; i < m; i += 512)
            atomicAdd(&hstart[((unsigned)staging[t + i].x) >> 16], 1);
        __syncthreads();
        // wave-0 shuffle scan over RB=64 bins (no block barriers)
        if (tid < 64) {
            int v = hstart[lane];
            int incl = v;
#pragma unroll
            for (int off = 1; off < 64; off <<= 1) {
                int tv = __shfl_up(incl, off, 64);
                if (lane >= off) incl += tv;
            }
            hstart[lane] = incl - v;     // exclusive
            hcur[lane]   = incl - v;
        }
        __syncthreads();
        for (int i = tid; i < m; i += 512) {
            int2 rc = staging[t + i];
            int pos = atomicAdd(&hcur[((unsigned)rc.x) >> 16], 1);
            sorted[pos] = rc;
        }
        __syncthreads();
        // gather: wave owns 8 nodes; register accumulate; owner-only acc adds
#pragma unroll
        for (int k = 0; k < 8; ++k) {
            int nl = wid * 8 + k;
            int beg = hstart[nl], end = hcur[nl];
            float a0 = 0.f, a1 = 0.f;
            for (int e = beg + p; e < end; e += 4) {
                int2 rc = sorted[e];                       // broadcast read
                float w = __int_as_float(rc.y);
                unsigned u = *reinterpret_cast<const unsigned*>(
                    sTb + (size_t)(rc.x & 0xffff) * 32 + 2 * q);
                a0 += w * __uint_as_float(u << 16);
                a1 += w * __uint_as_float(u & 0xffff0000u);
            }
            a0 += __shfl_xor(a0, 16, 64);
            a0 += __shfl_xor(a0, 32, 64);
            a1 += __shfl_xor(a1, 16, 64);
            a1 += __shfl_xor(a1, 32, 64);
            if (lane < 16) {                                // p == 0 lanes
                acc[nl * 33 + 2 * q]     += a0;
                acc[nl * 33 + 2 * q + 1] += a1;
            }
        }
        __syncthreads();
    }

    // epilogue: tanh / x-clamp, coalesced ns + y writes
    for (int v = tid; v < RB * BATCH; v += 512) {
        int nl = v & (RB - 1);
        int b  = v >> RB_LOG;
        int node = base + nl;
        if (node >= N) continue;
        float val;
        if (node < N_IN)
            val = x[b * N_IN + node];
        else
            val = tanhf(bias[node] + response[node] * acc[nl * 33 + b]);
        ns[(size_t)b * N + node] = val;
        int k = node - (N - N_OUT);
        if (k >= 0) y[b * N_OUT + k] = val;
    }
}

// ---- last-resort fallback (round-1) kernels ----
__global__ void edge_kernel_fb(const float* __restrict__ states,
                               const float* __restrict__ weight,
                               const int* __restrict__ edge_src,
                               const int* __restrict__ edge_dst,
                               float* __restrict__ agg, int E, int N) {
    int e = blockIdx.x * blockDim.x + threadIdx.x;
    if (e >= E) return;
    int s = edge_src[e];
    int d = edge_dst[e];
    float w = weight[e];
#pragma unroll
    for (int b = 0; b < BATCH; ++b)
        atomicAdd(agg + (size_t)b * N + d, w * states[(size_t)b * N + s]);
}

__global__ void finish_kernel_fb(const float* __restrict__ x,
                                 const float* __restrict__ agg,
                                 const float* __restrict__ bias,
                                 const float* __restrict__ response,
                                 float* __restrict__ y, float* __restrict__ ns,
                                 int N) {
    int n = blockIdx.x * blockDim.x + threadIdx.x;
    int b = blockIdx.y;
    if (n >= N) return;
    float v;
    if (n < N_IN) v = x[b * N_IN + n];
    else          v = tanhf(bias[n] + response[n] * agg[(size_t)b * N + n]);
    ns[(size_t)b * N + n] = v;
    int n0 = N - N_OUT;
    if (n >= n0) y[b * N_OUT + (n - n0)] = v;
}

extern "C" void kernel_launch(void* const* d_in, const int* in_sizes, int n_in,
                              void* d_out, int out_size, void* d_ws, size_t ws_size,
                              hipStream_t stream) {
    const float* x        = (const float*)d_in[0];
    const float* states   = (const float*)d_in[1];
    const float* weight   = (const float*)d_in[2];
    const float* bias     = (const float*)d_in[3];
    const float* response = (const float*)d_in[4];
    const int*   edge_src = (const int*)d_in[5];
    const int*   edge_dst = (const int*)d_in[6];

    int N = in_sizes[3];          // 50000
    int E = in_sizes[5];          // 800000

    float* y  = (float*)d_out;                   // (B, N_OUT)
    float* ns = (float*)d_out + BATCH * N_OUT;   // (B, N)

    int tgrid = (N + 31) / 32;                   // 1563
    int R  = (N + RB - 1) / RB;                  // 782
    int PB = (E + PCH - 1) / PCH;                // 98

    // slab capacity: 4x mean load, rounded up to CAPL multiple
    int mean = (E + R - 1) / R;                  // ~1023
    int CAP  = ((4 * mean + CAPL - 1) / CAPL) * CAPL;   // 4096

    size_t staging_bytes = ((size_t)R * CAP * 8 + 15) & ~(size_t)15;  // ~25.6MB
    size_t sTb_bytes     = ((size_t)N * 32 * 2 + 15) & ~(size_t)15;
    size_t cur_bytes     = ((size_t)R * 4 + 15) & ~(size_t)15;
    size_t needed = staging_bytes + sTb_bytes + cur_bytes + 64;

    if (ws_size < needed || R > MAXR || N > 65536) {
        // fallback: atomic-scatter path (needs 6.4 MB)
        float* agg = (float*)d_ws;
        hipMemsetAsync(agg, 0, (size_t)BATCH * N * sizeof(float), stream);
        int egrid = (E + 255) / 256;
        edge_kernel_fb<<<egrid, 256, 0, stream>>>(states, weight, edge_src,
                                                  edge_dst, agg, E, N);
        dim3 fgrid((N + 255) / 256, BATCH);
        finish_kernel_fb<<<fgrid, 256, 0, stream>>>(x, agg, bias, response,
                                                    y, ns, N);
        return;
    }

    char* p = (char*)d_ws;
    int2*           staging = (int2*)p;           p += staging_bytes;
    unsigned short* sTb     = (unsigned short*)p; p += sTb_bytes;
    int*            cursors = (int*)p;

    hipMemsetAsync(cursors, 0, (size_t)R * 4, stream);

    // K0: slab partition (blocks [0,PB)) || transpose (blocks [PB, PB+tgrid))
    fpart_kernel<<<PB + tgrid, 1024, 0, stream>>>(
        states, sTb, N, PB, edge_src, edge_dst, weight,
        cursors, staging, E, R, CAP);

    // K1: fused sort + register gather + tanh + output (all blocks co-resident)
    accfin_kernel<<<R, 512, 0, stream>>>(sTb, staging, cursors, x,
                                         bias, response, ns, y, N, CAP);
}

// Round 16
// 46.264 us; speedup vs baseline: 4.5554x; 1.0046x over previous
//
#include <hip/hip_runtime.h>

// WiredRNN one step. Slab partition + fused sort-gather-activate.
// NO f32 atomics (measured wall: 25.6M LDS f32 atomicAdd = 170-180us).
// r16: (1) accfin gather uses 8 record slots x 8B-row reads (halves the
//      per-node dependent-load chain); (2) fpart transpose does 4 tiles
//      per block (1563 -> 391 blocks).
// 3 dispatches: memset(cursors) ; fpart ; accfin.
// inputs: 0:x(B,512) 1:states(B,N) 2:weight(E) 3:bias(N) 4:response(N)
//         5:edge_src(E int32) 6:edge_dst(E int32)
// out: y(B,256) then new_states(B,N), f32, concatenated flat.

#define BATCH 32
#define N_IN 512
#define N_OUT 256
#define RB_LOG 6
#define RB 64            // nodes per range
#define CAPL 2048        // records sorted per accfin round (16KB LDS)
#define MAXR 2048        // max ranges for part LDS arrays
#define PCH 8192         // edges per partition block (8/thread)

static __device__ __forceinline__ unsigned short f2bf(float f) {
    unsigned u = __float_as_uint(f);
    unsigned r = (u + 0x7fffu + ((u >> 16) & 1u)) >> 16;   // RNE
    return (unsigned short)r;
}

// ---- K0: fused {slab partition} + {transpose (B,N)->(N,32) bf16, 4 tiles} ----
__global__ __launch_bounds__(1024)
void fpart_kernel(const float* __restrict__ s, unsigned short* __restrict__ sTb,
                  int N, int PB,
                  const int* __restrict__ edge_src,
                  const int* __restrict__ edge_dst,
                  const float* __restrict__ weight,
                  int* __restrict__ cursors,
                  int2* __restrict__ staging,
                  int E, int R, int CAP) {
    __shared__ int shbuf[4224];          // part: h+lcur (16KB); transpose: 4 tiles (16.9KB)
    int tid = threadIdx.x;
    if ((int)blockIdx.x >= PB) {
        // ------------- transpose: 4 tiles of 32 nodes -------------
        float* tiles = (float*)shbuf;    // [4][32*33]
        int tx = tid & 31;
        int ty = tid >> 5;               // 0..31 (= batch on load, node on store)
        int nb = ((int)blockIdx.x - PB) * 128;
#pragma unroll
        for (int t = 0; t < 4; ++t) {
            int n = nb + t * 32 + tx;
            tiles[t * 1056 + ty * 33 + tx] =
                (n < N) ? s[(size_t)ty * N + n] : 0.f;     // ty = b
        }
        __syncthreads();
#pragma unroll
        for (int t = 0; t < 4; ++t) {
            int nn = nb + t * 32 + ty;
            if (nn < N)
                sTb[(size_t)nn * 32 + tx] = f2bf(tiles[t * 1056 + tx * 33 + ty]);
        }
        return;
    }
    // ---------------- partition ----------------
    int* h    = shbuf;
    int* lcur = shbuf + MAXR;
    for (int i = tid; i < R; i += 1024) h[i] = 0;
    __syncthreads();
    int e0 = blockIdx.x * PCH;
    int e1 = min(e0 + PCH, E);
    int dd[8], ss[8]; float ww[8];
#pragma unroll
    for (int it = 0; it < 2; ++it) {
        int e = e0 + it * 4096 + tid * 4;
#pragma unroll
        for (int j = 0; j < 4; ++j) dd[it * 4 + j] = -1;
        if (e + 4 <= e1) {
            int4 d4 = *reinterpret_cast<const int4*>(edge_dst + e);
            int4 s4 = *reinterpret_cast<const int4*>(edge_src + e);
            float4 w4 = *reinterpret_cast<const float4*>(weight + e);
            dd[it*4+0]=d4.x; dd[it*4+1]=d4.y; dd[it*4+2]=d4.z; dd[it*4+3]=d4.w;
            ss[it*4+0]=s4.x; ss[it*4+1]=s4.y; ss[it*4+2]=s4.z; ss[it*4+3]=s4.w;
            ww[it*4+0]=w4.x; ww[it*4+1]=w4.y; ww[it*4+2]=w4.z; ww[it*4+3]=w4.w;
        } else {
#pragma unroll
            for (int j = 0; j < 4; ++j) {
                if (e + j < e1) {
                    dd[it*4+j] = edge_dst[e + j];
                    ss[it*4+j] = edge_src[e + j];
                    ww[it*4+j] = weight[e + j];
                }
            }
        }
#pragma unroll
        for (int j = 0; j < 4; ++j) {
            int idx = it * 4 + j;
            if (dd[idx] >= N_IN) atomicAdd(&h[dd[idx] >> RB_LOG], 1);
        }
    }
    __syncthreads();
    // reserve slab slices: one global atomic per non-empty (block, range)
    for (int i = tid; i < R; i += 1024) {
        int c = h[i];
        lcur[i] = c ? (i * CAP + atomicAdd(&cursors[i], c)) : 0;
    }
    __syncthreads();
    // place records from registers
#pragma unroll
    for (int idx = 0; idx < 8; ++idx) {
        if (dd[idx] >= N_IN) {
            int rng = dd[idx] >> RB_LOG;
            int pos = atomicAdd(&lcur[rng], 1);
            if (pos < (rng + 1) * CAP)   // overflow clamp (never at 4x mean)
                staging[pos] = make_int2(((dd[idx] & (RB - 1)) << 16) | ss[idx],
                                         __float_as_int(ww[idx]));
        }
    }
}

// ---- K1: per-range sort (LDS) + 8-slot register gather + activation ----
// 512 threads: 8 waves x 8 nodes; q=tid&7 (4 batches), p=(tid>>3)&7 (8 slots).
__global__ __launch_bounds__(512)
void accfin_kernel(const unsigned short* __restrict__ sTb,
                   const int2* __restrict__ staging,
                   const int* __restrict__ cursors,
                   const float* __restrict__ x,
                   const float* __restrict__ bias,
                   const float* __restrict__ response,
                   float* __restrict__ ns, float* __restrict__ y,
                   int N, int CAP) {
    __shared__ float acc[RB * 33];       // 8.4 KB, owner-wave writes only
    __shared__ int2  sorted[CAPL];       // 16 KB
    __shared__ int   hstart[RB];
    __shared__ int   hcur[RB];
    int tid = threadIdx.x;
    int r = blockIdx.x;
    int base = r * RB;
    for (int i = tid; i < RB * 33; i += 512) acc[i] = 0.f;

    int b0 = r * CAP;
    int b1 = b0 + min(cursors[r], CAP);
    int q = tid & 7;                     // batches 4q .. 4q+3
    int p = (tid >> 3) & 7;              // record slot 0..7
    int wid = tid >> 6;                  // wave -> nodes [wid*8, wid*8+8)
    int lane = tid & 63;

    for (int t = b0; t < b1; t += CAPL) {
        int m = min(CAPL, b1 - t);
        if (tid < RB) hstart[tid] = 0;
        __syncthreads();
        for (int i = tid; i < m; i += 512)
            atomicAdd(&hstart[((unsigned)staging[t + i].x) >> 16], 1);
        __syncthreads();
        // wave-0 shuffle scan over RB=64 bins (no block barriers)
        if (tid < 64) {
            int v = hstart[lane];
            int incl = v;
#pragma unroll
            for (int off = 1; off < 64; off <<= 1) {
                int tv = __shfl_up(incl, off, 64);
                if (lane >= off) incl += tv;
            }
            hstart[lane] = incl - v;     // exclusive
            hcur[lane]   = incl - v;
        }
        __syncthreads();
        for (int i = tid; i < m; i += 512) {
            int2 rc = staging[t + i];
            int pos = atomicAdd(&hcur[((unsigned)rc.x) >> 16], 1);
            sorted[pos] = rc;
        }
        __syncthreads();
        // gather: wave owns 8 nodes; 8 slots in flight; owner-only acc adds
#pragma unroll
        for (int k = 0; k < 8; ++k) {
            int nl = wid * 8 + k;
            int beg = hstart[nl], end = hcur[nl];
            float a0 = 0.f, a1 = 0.f, a2 = 0.f, a3 = 0.f;
            for (int e = beg + p; e < end; e += 8) {
                int2 rc = sorted[e];                       // broadcast read
                float w = __int_as_float(rc.y);
                uint2 u2 = *reinterpret_cast<const uint2*>(
                    sTb + (size_t)(rc.x & 0xffff) * 32 + 4 * q);
                a0 += w * __uint_as_float(u2.x << 16);
                a1 += w * __uint_as_float(u2.x & 0xffff0000u);
                a2 += w * __uint_as_float(u2.y << 16);
                a3 += w * __uint_as_float(u2.y & 0xffff0000u);
            }
#pragma unroll
            for (int off = 8; off < 64; off <<= 1) {
                a0 += __shfl_xor(a0, off, 64);
                a1 += __shfl_xor(a1, off, 64);
                a2 += __shfl_xor(a2, off, 64);
                a3 += __shfl_xor(a3, off, 64);
            }
            if (lane < 8) {                                 // p == 0 lanes
                float* ap = &acc[nl * 33 + 4 * q];
                ap[0] += a0; ap[1] += a1; ap[2] += a2; ap[3] += a3;
            }
        }
        __syncthreads();
    }

    // epilogue: tanh / x-clamp, coalesced ns + y writes
    for (int v = tid; v < RB * BATCH; v += 512) {
        int nl = v & (RB - 1);
        int b  = v >> RB_LOG;
        int node = base + nl;
        if (node >= N) continue;
        float val;
        if (node < N_IN)
            val = x[b * N_IN + node];
        else
            val = tanhf(bias[node] + response[node] * acc[nl * 33 + b]);
        ns[(size_t)b * N + node] = val;
        int k = node - (N - N_OUT);
        if (k >= 0) y[b * N_OUT + k] = val;
    }
}

// ---- last-resort fallback (round-1) kernels ----
__global__ void edge_kernel_fb(const float* __restrict__ states,
                               const float* __restrict__ weight,
                               const int* __restrict__ edge_src,
                               const int* __restrict__ edge_dst,
                               float* __restrict__ agg, int E, int N) {
    int e = blockIdx.x * blockDim.x + threadIdx.x;
    if (e >= E) return;
    int s = edge_src[e];
    int d = edge_dst[e];
    float w = weight[e];
#pragma unroll
    for (int b = 0; b < BATCH; ++b)
        atomicAdd(agg + (size_t)b * N + d, w * states[(size_t)b * N + s]);
}

__global__ void finish_kernel_fb(const float* __restrict__ x,
                                 const float* __restrict__ agg,
                                 const float* __restrict__ bias,
                                 const float* __restrict__ response,
                                 float* __restrict__ y, float* __restrict__ ns,
                                 int N) {
    int n = blockIdx.x * blockDim.x + threadIdx.x;
    int b = blockIdx.y;
    if (n >= N) return;
    float v;
    if (n < N_IN) v = x[b * N_IN + n];
    else          v = tanhf(bias[n] + response[n] * agg[(size_t)b * N + n]);
    ns[(size_t)b * N + n] = v;
    int n0 = N - N_OUT;
    if (n >= n0) y[b * N_OUT + (n - n0)] = v;
}

extern "C" void kernel_launch(void* const* d_in, const int* in_sizes, int n_in,
                              void* d_out, int out_size, void* d_ws, size_t ws_size,
                              hipStream_t stream) {
    const float* x        = (const float*)d_in[0];
    const float* states   = (const float*)d_in[1];
    const float* weight   = (const float*)d_in[2];
    const float* bias     = (const float*)d_in[3];
    const float* response = (const float*)d_in[4];
    const int*   edge_src = (const int*)d_in[5];
    const int*   edge_dst = (const int*)d_in[6];

    int N = in_sizes[3];          // 50000
    int E = in_sizes[5];          // 800000

    float* y  = (float*)d_out;                   // (B, N_OUT)
    float* ns = (float*)d_out + BATCH * N_OUT;   // (B, N)

    int tgrid4 = (N + 127) / 128;                // 391
    int R  = (N + RB - 1) / RB;                  // 782
    int PB = (E + PCH - 1) / PCH;                // 98

    // slab capacity: 4x mean load, rounded up to CAPL multiple
    int mean = (E + R - 1) / R;                  // ~1023
    int CAP  = ((4 * mean + CAPL - 1) / CAPL) * CAPL;   // 4096

    size_t staging_bytes = ((size_t)R * CAP * 8 + 15) & ~(size_t)15;  // ~25.6MB
    size_t sTb_bytes     = ((size_t)N * 32 * 2 + 15) & ~(size_t)15;
    size_t cur_bytes     = ((size_t)R * 4 + 15) & ~(size_t)15;
    size_t needed = staging_bytes + sTb_bytes + cur_bytes + 64;

    if (ws_size < needed || R > MAXR || N > 65536) {
        // fallback: atomic-scatter path (needs 6.4 MB)
        float* agg = (float*)d_ws;
        hipMemsetAsync(agg, 0, (size_t)BATCH * N * sizeof(float), stream);
        int egrid = (E + 255) / 256;
        edge_kernel_fb<<<egrid, 256, 0, stream>>>(states, weight, edge_src,
                                                  edge_dst, agg, E, N);
        dim3 fgrid((N + 255) / 256, BATCH);
        finish_kernel_fb<<<fgrid, 256, 0, stream>>>(x, agg, bias, response,
                                                    y, ns, N);
        return;
    }

    char* p = (char*)d_ws;
    int2*           staging = (int2*)p;           p += staging_bytes;
    unsigned short* sTb     = (unsigned short*)p; p += sTb_bytes;
    int*            cursors = (int*)p;

    hipMemsetAsync(cursors, 0, (size_t)R * 4, stream);

    // K0: slab partition (blocks [0,PB)) || transpose x4 (blocks [PB, PB+tgrid4))
    fpart_kernel<<<PB + tgrid4, 1024, 0, stream>>>(
        states, sTb, N, PB, edge_src, edge_dst, weight,
        cursors, staging, E, R, CAP);

    // K1: fused sort + 8-slot register gather + tanh + output
    accfin_kernel<<<R, 512, 0, stream>>>(sTb, staging, cursors, x,
                                         bias, response, ns, y, N, CAP);
}